// Round 12
// baseline (148.652 us; speedup 1.0000x reference)
//
#include <hip/hip_runtime.h>
#include <hip/hip_bf16.h>
#include <cstdint>

typedef __attribute__((ext_vector_type(4))) float f32x4;
typedef __attribute__((ext_vector_type(8))) short bf16x8;

__device__ __forceinline__ ushort f2bf(float f) {
  unsigned u = __builtin_bit_cast(unsigned, f);
  u += 0x7fffu + ((u >> 16) & 1u);
  return (ushort)(u >> 16);
}

__device__ __forceinline__ unsigned cvt2(float a, float b) {
  return (unsigned)f2bf(a) | ((unsigned)f2bf(b) << 16);
}

__device__ __forceinline__ void gload_lds16(const ushort* g, ushort* l) {
  __builtin_amdgcn_global_load_lds(
      (const __attribute__((address_space(1))) unsigned int*)g,
      (__attribute__((address_space(3))) unsigned int*)l, 16, 0, 0);
}

__device__ __forceinline__ void hard_barrier() {
  __builtin_amdgcn_sched_barrier(0);
  __builtin_amdgcn_s_barrier();
  __builtin_amdgcn_sched_barrier(0);
}

__device__ __forceinline__ void wait_lgkm0() {
  asm volatile("s_waitcnt lgkmcnt(0)" ::: "memory");
}

template <int N>
__device__ __forceinline__ void wait_vm() {
  if constexpr (N == 0) asm volatile("s_waitcnt vmcnt(0)" ::: "memory");
  else if constexpr (N == 2) asm volatile("s_waitcnt vmcnt(2)" ::: "memory");
  else if constexpr (N == 4) asm volatile("s_waitcnt vmcnt(4)" ::: "memory");
  else if constexpr (N == 6) asm volatile("s_waitcnt vmcnt(6)" ::: "memory");
  else if constexpr (N == 8) asm volatile("s_waitcnt vmcnt(8)" ::: "memory");
  else static_assert(N < 0, "unsupported vmcnt");
}

__device__ __forceinline__ float elu1(float v) {
  return (v > 0.f) ? (v + 1.f) : __expf(v);
}

// ---------- kernel 0: W_qkv [1024][1536] f32 -> Wt [1536][1024] bf16 ----------
__global__ __launch_bounds__(256) void transpose_w_kernel(const float* __restrict__ W,
                                                          ushort* __restrict__ Wt) {
  __shared__ float tile[32][33];
  int n0 = blockIdx.x * 32;
  int k0 = blockIdx.y * 32;
  int tx = threadIdx.x;  // 0..31
  int ty = threadIdx.y;  // 0..7
  #pragma unroll
  for (int p = 0; p < 4; ++p) {
    int k = k0 + ty + p * 8;
    tile[ty + p * 8][tx] = W[(size_t)k * 1536 + n0 + tx];
  }
  __syncthreads();
  #pragma unroll
  for (int p = 0; p < 4; ++p) {
    int n = n0 + ty + p * 8;
    Wt[(size_t)n * 1024 + k0 + tx] = f2bf(tile[tx][ty + p * 8]);
  }
}

// ============================================================================
// R1 core (bf16 A and B via global_load_lds) — used by gemm_out. Measured:
// 831 TF class, 0 bank conflicts. 128x256 tile, BK=64, 512 thr = 8 waves,
// 3 slots x 48KB; counted vmcnt(6); swizzle phys slot = logical ^ (row&7).
// ============================================================================
template <int LDA, int LDB, int NT>
__device__ __forceinline__ void gemm_core(const ushort* __restrict__ A,
                                          const ushort* __restrict__ Bt,
                                          int row0, int col0, f32x4 acc[4][4],
                                          ushort* lds) {
  const int tid = threadIdx.x;
  const int l = tid & 63;
  const int wid = tid >> 6;
  const int fr = l & 15;
  const int fq = l >> 4;
  const int wr = wid >> 2;
  const int wc = wid & 3;

  const int scol = ((l & 7) * 8) ^ (((l >> 3) & 7) * 8);
  const ushort* aS = A + (size_t)(row0 + (tid >> 3)) * LDA + scol;
  const ushort* bS = Bt + (size_t)(col0 + (tid >> 3)) * LDB + scol;

  int aRow[4], bRow[4], kx[2];
  #pragma unroll
  for (int m = 0; m < 4; ++m) aRow[m] = (wr * 64 + m * 16 + fr) * 64;
  #pragma unroll
  for (int n = 0; n < 4; ++n) bRow[n] = (wc * 64 + n * 16 + fr) * 64;
  #pragma unroll
  for (int ks = 0; ks < 2; ++ks) kx[ks] = (ks * 32 + fq * 8) ^ ((fr & 7) * 8);

  auto stage = [&](int t) {
    ushort* dst = lds + (t % 3) * 24576 + tid * 8;
    const int ko = t * 64;
    #pragma unroll
    for (int p = 0; p < 2; ++p)
      gload_lds16(aS + (size_t)(p * 64) * LDA + ko, dst + p * 4096);
    #pragma unroll
    for (int p = 0; p < 4; ++p)
      gload_lds16(bS + (size_t)(p * 64) * LDB + ko, dst + 8192 + p * 4096);
  };

  stage(0);
  stage(1);
  wait_vm<6>();
  hard_barrier();

  #pragma unroll
  for (int t = 0; t < NT; ++t) {
    if (t + 2 < NT) stage(t + 2);
    const ushort* aB = lds + (t % 3) * 24576;
    const ushort* bB = aB + 8192;
    #pragma unroll
    for (int ks = 0; ks < 2; ++ks) {
      bf16x8 av[4], bv[4];
      #pragma unroll
      for (int m = 0; m < 4; ++m) av[m] = *(const bf16x8*)&aB[aRow[m] + kx[ks]];
      #pragma unroll
      for (int n = 0; n < 4; ++n) bv[n] = *(const bf16x8*)&bB[bRow[n] + kx[ks]];
      __builtin_amdgcn_s_setprio(1);
      #pragma unroll
      for (int m = 0; m < 4; ++m)
        #pragma unroll
        for (int n = 0; n < 4; ++n)
          acc[m][n] = __builtin_amdgcn_mfma_f32_16x16x32_bf16(av[m], bv[n], acc[m][n], 0, 0, 0);
      __builtin_amdgcn_s_setprio(0);
    }
    if (t + 2 < NT) {
      wait_vm<6>();
      hard_barrier();
    } else if (t + 1 < NT) {
      wait_vm<0>();
      hard_barrier();
    }
  }
}

// ---------- kernel 1: qkv GEMM reading x FP32 directly ----------
// A-staging: 4x global_load_dwordx4 (fp32) -> packed cvt -> 2x 16B ds_write
// to the same swizzled-linear LDS addresses as the gload_lds path. B (wt bf16)
// stays global_load_lds. Schedule per K-tile t:
//   issue(t+2) [4 A-loads + 4 B-glds = 8 vm ops]; compute(t);
//   vmcnt(8) -> tile t+1's A-regs + B-LDS certified; writeA(t+1) (cvt+ds_write);
//   lgkmcnt(0); barrier  (raw s_barrier needs the explicit lgkm drain).
// WAR: writeA(t+1)/issueB(t+1) target slot (t+1)%3, prev tenant t-2 done 2
// barriers ago. va[2] double-buffer indices static under full unroll.
// Epilogue emits q (elu+1) row-major, kT (elu+1) / vT n-major.
__global__ __launch_bounds__(512, 2) void gemm_qkv_kernel(const float* __restrict__ x,
                                                          const ushort* __restrict__ wt,
                                                          ushort* __restrict__ q,
                                                          ushort* __restrict__ kT,
                                                          ushort* __restrict__ vT) {
  __shared__ ushort lds[73728];  // 144 KiB
  constexpr int LDA = 1024, LDB = 1024, NT = 16;
  f32x4 acc[4][4] = {};
  const int row0 = blockIdx.x * 128;
  const int col0 = blockIdx.y * 256;

  const int tid = threadIdx.x;
  const int l = tid & 63;
  const int wid = tid >> 6;
  const int fr = l & 15;
  const int fq = l >> 4;
  const int wr = wid >> 2;
  const int wc = wid & 3;

  const int scol = ((l & 7) * 8) ^ (((l >> 3) & 7) * 8);
  const float* aS = x + (size_t)(row0 + (tid >> 3)) * LDA + scol;
  const ushort* bS = wt + (size_t)(col0 + (tid >> 3)) * LDB + scol;

  int aRow[4], bRow[4], kx[2];
  #pragma unroll
  for (int m = 0; m < 4; ++m) aRow[m] = (wr * 64 + m * 16 + fr) * 64;
  #pragma unroll
  for (int n = 0; n < 4; ++n) bRow[n] = (wc * 64 + n * 16 + fr) * 64;
  #pragma unroll
  for (int ks = 0; ks < 2; ++ks) kx[ks] = (ks * 32 + fq * 8) ^ ((fr & 7) * 8);

  float4 va[2][4];  // [tile parity][p*2 + half] — indices static after unroll

  auto issueT = [&](int t) {
    const float* s = aS + t * 64;
    #pragma unroll
    for (int p = 0; p < 2; ++p) {
      va[t & 1][p * 2]     = *(const float4*)(s + (size_t)(p * 64) * LDA);
      va[t & 1][p * 2 + 1] = *(const float4*)(s + (size_t)(p * 64) * LDA + 4);
    }
    ushort* dst = lds + (t % 3) * 24576 + 8192 + tid * 8;
    const int ko = t * 64;
    #pragma unroll
    for (int p = 0; p < 4; ++p)
      gload_lds16(bS + (size_t)(p * 64) * LDB + ko, dst + p * 4096);
  };

  auto writeA = [&](int t) {
    ushort* dst = lds + (t % 3) * 24576 + tid * 8;
    #pragma unroll
    for (int p = 0; p < 2; ++p) {
      const float4 lo = va[t & 1][p * 2];
      const float4 hi = va[t & 1][p * 2 + 1];
      uint4 w;
      w.x = cvt2(lo.x, lo.y);
      w.y = cvt2(lo.z, lo.w);
      w.z = cvt2(hi.x, hi.y);
      w.w = cvt2(hi.z, hi.w);
      *(uint4*)(dst + p * 4096) = w;
    }
  };

  auto compute = [&](int t) {
    const ushort* aB = lds + (t % 3) * 24576;
    const ushort* bB = aB + 8192;
    #pragma unroll
    for (int ks = 0; ks < 2; ++ks) {
      bf16x8 av[4], bv[4];
      #pragma unroll
      for (int m = 0; m < 4; ++m) av[m] = *(const bf16x8*)&aB[aRow[m] + kx[ks]];
      #pragma unroll
      for (int n = 0; n < 4; ++n) bv[n] = *(const bf16x8*)&bB[bRow[n] + kx[ks]];
      __builtin_amdgcn_s_setprio(1);
      #pragma unroll
      for (int m = 0; m < 4; ++m)
        #pragma unroll
        for (int n = 0; n < 4; ++n)
          acc[m][n] = __builtin_amdgcn_mfma_f32_16x16x32_bf16(av[m], bv[n], acc[m][n], 0, 0, 0);
      __builtin_amdgcn_s_setprio(0);
    }
  };

  // prologue
  issueT(0);
  issueT(1);
  wait_vm<8>();  // tile0's A-regs + B-LDS landed
  writeA(0);
  wait_lgkm0();
  hard_barrier();

  #pragma unroll
  for (int t = 0; t < NT; ++t) {
    if (t + 2 < NT) issueT(t + 2);
    compute(t);
    if (t + 1 < NT) {
      if (t + 2 < NT) wait_vm<8>();
      else wait_vm<0>();
      writeA(t + 1);
      wait_lgkm0();
      hard_barrier();
    }
  }

  // ---- epilogue (R8/R10 verbatim) ----
  #pragma unroll
  for (int m = 0; m < 4; ++m) {
    #pragma unroll
    for (int n = 0; n < 4; ++n) {
      const int c = col0 + wc * 64 + n * 16 + fr;
      const int r0 = row0 + wr * 64 + m * 16 + fq * 4;
      if (c < 512) {
        #pragma unroll
        for (int j = 0; j < 4; ++j)
          q[(size_t)(r0 + j) * 512 + c] = f2bf(elu1(acc[m][n][j]));
      } else if (c < 1024) {
        const int d = c - 512;
        const int bh = (r0 >> 12) * 8 + (d >> 6);
        const int nn = r0 & 4095;
        ushort4 o;
        o.x = f2bf(elu1(acc[m][n][0]));
        o.y = f2bf(elu1(acc[m][n][1]));
        o.z = f2bf(elu1(acc[m][n][2]));
        o.w = f2bf(elu1(acc[m][n][3]));
        *(ushort4*)&kT[((size_t)bh * 64 + (d & 63)) * 4096 + nn] = o;
      } else {
        const int d = c - 1024;
        const int bh = (r0 >> 12) * 8 + (d >> 6);
        const int nn = r0 & 4095;
        ushort4 o;
        o.x = f2bf(acc[m][n][0]);
        o.y = f2bf(acc[m][n][1]);
        o.z = f2bf(acc[m][n][2]);
        o.w = f2bf(acc[m][n][3]);
        *(ushort4*)&vT[((size_t)bh * 64 + (d & 63)) * 4096 + nn] = o;
      }
    }
  }
}

// ---------- kernel 2: ctx partials via MFMA (R10 verbatim) ----------
__global__ __launch_bounds__(256) void ctx_mfma_kernel(const ushort* __restrict__ kT,
                                                       const ushort* __restrict__ vT,
                                                       float* __restrict__ part) {
  __shared__ ushort lds[16384];  // 32 KiB
  const int bh = blockIdx.x;
  const int sp = blockIdx.y;
  const int tid = threadIdx.x;
  const int l = tid & 63, wid = tid >> 6;
  const int fr = l & 15, fq = l >> 4;
  const int wr = wid >> 1, wc = wid & 1;

  const size_t base = (size_t)bh * 64 * 4096 + sp * 512;
  const int srow = tid >> 2;                     // 0..63
  const int lam = (tid & 3) ^ ((tid >> 3) & 3);  // logical 16B slot for phys (tid&3)
  const ushort* aG = kT + base + (size_t)srow * 4096 + lam * 8;
  const ushort* bG = vT + base + (size_t)srow * 4096 + lam * 8;

  auto stage = [&](int t) {
    ushort* d = lds + (t & 3) * 4096 + tid * 8;
    gload_lds16(aG + t * 32, d);
    gload_lds16(bG + t * 32, d + 2048);
  };

  const int sig = fq ^ ((fr >> 1) & 3);
  f32x4 acc[2][2] = {};

  auto compute = [&](int t) {
    const ushort* sb = lds + (t & 3) * 4096;
    bf16x8 av[2], bv[2];
    #pragma unroll
    for (int mm = 0; mm < 2; ++mm)
      av[mm] = *(const bf16x8*)&sb[(wr * 32 + mm * 16 + fr) * 32 + sig * 8];
    #pragma unroll
    for (int nn = 0; nn < 2; ++nn)
      bv[nn] = *(const bf16x8*)&sb[2048 + (wc * 32 + nn * 16 + fr) * 32 + sig * 8];
    #pragma unroll
    for (int mm = 0; mm < 2; ++mm)
      #pragma unroll
      for (int nn = 0; nn < 2; ++nn)
        acc[mm][nn] = __builtin_amdgcn_mfma_f32_16x16x32_bf16(av[mm], bv[nn], acc[mm][nn], 0, 0, 0);
  };

  constexpr int NT = 16;
  stage(0); stage(1); stage(2);
  for (int t = 0; t < NT; ++t) {
    if (t <= NT - 3) wait_vm<4>();
    else if (t == NT - 2) wait_vm<2>();
    else wait_vm<0>();
    hard_barrier();
    compute(t);
    hard_barrier();
    if (t + 3 < NT) stage(t + 3);
  }

  float* dst = part + ((size_t)sp * 32 + bh) * 4096;
  #pragma unroll
  for (int mm = 0; mm < 2; ++mm)
    #pragma unroll
    for (int nn = 0; nn < 2; ++nn)
      #pragma unroll
      for (int j = 0; j < 4; ++j)
        dst[(wr * 32 + mm * 16 + fq * 4 + j) * 64 + wc * 32 + nn * 16 + fr] = acc[mm][nn][j];
}

// ---------- kernel 3: W_eff^T (folds the 8-way split reduction) ----------
__global__ __launch_bounds__(256) void weff_kernel(const float* __restrict__ part,
                                                   const float* __restrict__ Wout,
                                                   ushort* __restrict__ weff) {
  const int bh = blockIdx.x;  // b*8+h
  const int h = bh & 7;
  const int m0 = blockIdx.y * 128;
  const int t = threadIdx.x;
  __shared__ float cs[64 * 64];
  __shared__ float ws[64][128];
  #pragma unroll
  for (int p = 0; p < 4; ++p) {
    const int idx = p * 1024 + t * 4;
    f32x4 s = {};
    #pragma unroll
    for (int sp = 0; sp < 8; ++sp)
      s += *(const f32x4*)&part[(size_t)sp * 131072 + (size_t)bh * 4096 + idx];
    *(f32x4*)&cs[idx] = s;
  }
  #pragma unroll
  for (int p = 0; p < 8; ++p) {
    const int e = (t >> 5) + p * 8;
    const int c = (t & 31) * 4;
    *(float4*)&ws[e][c] = *(const float4*)&Wout[(size_t)(h * 64 + e) * 1024 + m0 + c];
  }
  __syncthreads();
  const int m = t & 127;
  const int dh = (t >> 7) * 32;
  float acc[32] = {};
  for (int e = 0; e < 64; ++e) {
    const float w = ws[e][m];
    #pragma unroll
    for (int i = 0; i < 32; ++i)
      acc[i] += cs[(dh + i) * 64 + e] * w;
  }
  ushort* dst = weff + ((size_t)(bh >> 3) * 1024 + m0 + m) * 512 + h * 64 + dh;
  #pragma unroll
  for (int i = 0; i < 32; ++i) dst[i] = f2bf(acc[i]);
}

// ---------- kernel 4: out = q @ W_eff^T + b_out (fp32 out) ----------
__global__ __launch_bounds__(512, 2) void gemm_out_kernel(const ushort* __restrict__ q,
                                                          const ushort* __restrict__ weff,
                                                          const float* __restrict__ bout,
                                                          float* __restrict__ out) {
  __shared__ ushort lds[73728];  // 144 KiB
  f32x4 acc[4][4] = {};
  const int row0 = blockIdx.x * 128;
  const int col0 = blockIdx.y * 256;
  const int b = row0 >> 12;  // row0 / 4096
  gemm_core<512, 512, 8>(q, weff + (size_t)b * 1024 * 512, row0, col0, acc, lds);
  const int l = threadIdx.x & 63;
  const int wid = threadIdx.x >> 6;
  const int wr = wid >> 2, wc = wid & 3;
  const int fr = l & 15, fq = l >> 4;
  #pragma unroll
  for (int m = 0; m < 4; ++m) {
    #pragma unroll
    for (int n = 0; n < 4; ++n) {
      const int c = col0 + wc * 64 + n * 16 + fr;
      const float bb = bout[c];
      #pragma unroll
      for (int j = 0; j < 4; ++j) {
        const int r = row0 + wr * 64 + m * 16 + fq * 4 + j;
        out[(size_t)r * 1024 + c] = acc[m][n][j] + bb;
      }
    }
  }
}

extern "C" void kernel_launch(void* const* d_in, const int* in_sizes, int n_in,
                              void* d_out, int out_size, void* d_ws, size_t ws_size,
                              hipStream_t stream) {
  const float* x    = (const float*)d_in[0];
  const float* Wqkv = (const float*)d_in[1];
  const float* Wout = (const float*)d_in[2];
  const float* bout = (const float*)d_in[3];
  float* out = (float*)d_out;
  char* ws = (char*)d_ws;

  // workspace layout (bytes) — same proven offsets as R10 (xb region now holds part only)
  float*  part = (float* )(ws);              // 8*32*4096*4   = 4194304
  ushort* wt   = (ushort*)(ws + 33554432);   // 1536*1024*2   = 3145728
  ushort* q    = (ushort*)(ws + 36700160);   // 16384*512*2   = 16777216
  ushort* kT   = (ushort*)(ws + 53477376);   // 32*64*4096*2  = 16777216
  ushort* vT   = (ushort*)(ws + 70254592);   // 32*64*4096*2  = 16777216
  ushort* weff = (ushort*)(ws + 87556096);   // 4*1024*512*2  = 4194304

  transpose_w_kernel<<<dim3(48, 32), dim3(32, 8), 0, stream>>>(Wqkv, wt);
  gemm_qkv_kernel<<<dim3(128, 6), 512, 0, stream>>>(x, wt, q, kT, vT);
  ctx_mfma_kernel<<<dim3(32, 8), 256, 0, stream>>>(kT, vT, part);
  weff_kernel<<<dim3(32, 8), 256, 0, stream>>>(part, Wout, weff);
  gemm_out_kernel<<<dim3(128, 4), 512, 0, stream>>>(q, weff, bout, out);
}

// Round 13
// 140.801 us; speedup vs baseline: 1.0558x; 1.0558x over previous
//
#include <hip/hip_runtime.h>
#include <hip/hip_bf16.h>
#include <cstdint>

typedef __attribute__((ext_vector_type(4))) float f32x4;
typedef __attribute__((ext_vector_type(8))) short bf16x8;

__device__ __forceinline__ ushort f2bf(float f) {
  unsigned u = __builtin_bit_cast(unsigned, f);
  u += 0x7fffu + ((u >> 16) & 1u);
  return (ushort)(u >> 16);
}

__device__ __forceinline__ void gload_lds16(const ushort* g, ushort* l) {
  __builtin_amdgcn_global_load_lds(
      (const __attribute__((address_space(1))) unsigned int*)g,
      (__attribute__((address_space(3))) unsigned int*)l, 16, 0, 0);
}

__device__ __forceinline__ void hard_barrier() {
  __builtin_amdgcn_sched_barrier(0);
  __builtin_amdgcn_s_barrier();
  __builtin_amdgcn_sched_barrier(0);
}

template <int N>
__device__ __forceinline__ void wait_vm() {
  if constexpr (N == 0) asm volatile("s_waitcnt vmcnt(0)" ::: "memory");
  else if constexpr (N == 2) asm volatile("s_waitcnt vmcnt(2)" ::: "memory");
  else if constexpr (N == 4) asm volatile("s_waitcnt vmcnt(4)" ::: "memory");
  else if constexpr (N == 6) asm volatile("s_waitcnt vmcnt(6)" ::: "memory");
  else static_assert(N < 0, "unsupported vmcnt");
}

__device__ __forceinline__ float elu1(float v) {
  return (v > 0.f) ? (v + 1.f) : __expf(v);
}

// ---------- kernel 0: fused prep (R10 verbatim) ----------
__global__ __launch_bounds__(256) void prep_kernel(const float4* __restrict__ x,
                                                   ushort4* __restrict__ xb,
                                                   const float* __restrict__ W,
                                                   ushort* __restrict__ Wt) {
  if (blockIdx.x < 2048) {
    const int n4 = 16384 * 1024 / 4;
    const int stride = 2048 * 256;
    for (int i = blockIdx.x * 256 + threadIdx.x; i < n4; i += stride) {
      float4 f = x[i];
      ushort4 o;
      o.x = f2bf(f.x); o.y = f2bf(f.y); o.z = f2bf(f.z); o.w = f2bf(f.w);
      xb[i] = o;
    }
  } else {
    __shared__ float tile[32][33];
    const int tb = blockIdx.x - 2048;     // 0..1535
    const int n0 = (tb % 48) * 32;
    const int k0 = (tb / 48) * 32;
    const int tx = threadIdx.x & 31;
    const int ty = threadIdx.x >> 5;      // 0..7
    #pragma unroll
    for (int p = 0; p < 4; ++p) {
      int k = k0 + ty + p * 8;
      tile[ty + p * 8][tx] = W[(size_t)k * 1536 + n0 + tx];
    }
    __syncthreads();
    #pragma unroll
    for (int p = 0; p < 4; ++p) {
      int n = n0 + ty + p * 8;
      Wt[(size_t)n * 1024 + k0 + tx] = f2bf(tile[tx][ty + p * 8]);
    }
  }
}

// ============================================================================
// R1 core (measured best: 831 TF, 0 bank conflicts): 128x256 tile, BK=64,
// 512 threads = 8 waves (2M x 4N), wave tile 64x64. 3 LDS slots of 48KB;
// single barrier per K-tile; counted vmcnt(6); setprio on MFMA. Swizzle:
// phys 16B slot = logical ^ (row&7), pre-swizzled global source (rule #21).
// ============================================================================
template <int LDA, int LDB, int NT>
__device__ __forceinline__ void gemm_core(const ushort* __restrict__ A,
                                          const ushort* __restrict__ Bt,
                                          int row0, int col0, f32x4 acc[4][4],
                                          ushort* lds) {
  const int tid = threadIdx.x;
  const int l = tid & 63;
  const int wid = tid >> 6;
  const int fr = l & 15;
  const int fq = l >> 4;
  const int wr = wid >> 2;
  const int wc = wid & 3;

  const int scol = ((l & 7) * 8) ^ (((l >> 3) & 7) * 8);
  const ushort* aS = A + (size_t)(row0 + (tid >> 3)) * LDA + scol;
  const ushort* bS = Bt + (size_t)(col0 + (tid >> 3)) * LDB + scol;

  int aRow[4], bRow[4], kx[2];
  #pragma unroll
  for (int m = 0; m < 4; ++m) aRow[m] = (wr * 64 + m * 16 + fr) * 64;
  #pragma unroll
  for (int n = 0; n < 4; ++n) bRow[n] = (wc * 64 + n * 16 + fr) * 64;
  #pragma unroll
  for (int ks = 0; ks < 2; ++ks) kx[ks] = (ks * 32 + fq * 8) ^ ((fr & 7) * 8);

  auto stage = [&](int t) {
    ushort* dst = lds + (t % 3) * 24576 + tid * 8;
    const int ko = t * 64;
    #pragma unroll
    for (int p = 0; p < 2; ++p)
      gload_lds16(aS + (size_t)(p * 64) * LDA + ko, dst + p * 4096);
    #pragma unroll
    for (int p = 0; p < 4; ++p)
      gload_lds16(bS + (size_t)(p * 64) * LDB + ko, dst + 8192 + p * 4096);
  };

  stage(0);
  stage(1);
  wait_vm<6>();
  hard_barrier();

  #pragma unroll
  for (int t = 0; t < NT; ++t) {
    if (t + 2 < NT) stage(t + 2);
    const ushort* aB = lds + (t % 3) * 24576;
    const ushort* bB = aB + 8192;
    #pragma unroll
    for (int ks = 0; ks < 2; ++ks) {
      bf16x8 av[4], bv[4];
      #pragma unroll
      for (int m = 0; m < 4; ++m) av[m] = *(const bf16x8*)&aB[aRow[m] + kx[ks]];
      #pragma unroll
      for (int n = 0; n < 4; ++n) bv[n] = *(const bf16x8*)&bB[bRow[n] + kx[ks]];
      __builtin_amdgcn_s_setprio(1);
      #pragma unroll
      for (int m = 0; m < 4; ++m)
        #pragma unroll
        for (int n = 0; n < 4; ++n)
          acc[m][n] = __builtin_amdgcn_mfma_f32_16x16x32_bf16(av[m], bv[n], acc[m][n], 0, 0, 0);
      __builtin_amdgcn_s_setprio(0);
    }
    if (t + 2 < NT) {
      wait_vm<6>();
      hard_barrier();
    } else if (t + 1 < NT) {
      wait_vm<0>();
      hard_barrier();
    }
  }
}

// ---------- kernel 1: qkv GEMM; LDS-bounce epilogue ----------
// Each block's 256-col panel is entirely one region (by 0,1=q; 2,3=k; 4,5=v).
// After the K-loop (all gload_lds drained by the tail vmcnt(0)), the acc tile
// is written to LDS bf16 [128][pitch 264] (elu applied for q/k), then stored:
//   q: 4 threads/row emit 512B-contiguous row segments of q[16384][512].
//   k/v: each lane owns one feature column (LDS col reads 2-way free),
//        emits 16B token-contiguous stores to kT/vT [bh][64][4096].
__global__ __launch_bounds__(512, 2) void gemm_qkv_kernel(const ushort* __restrict__ xb,
                                                          const ushort* __restrict__ wt,
                                                          ushort* __restrict__ q,
                                                          ushort* __restrict__ kT,
                                                          ushort* __restrict__ vT) {
  __shared__ ushort lds[73728];  // 144 KiB
  f32x4 acc[4][4] = {};
  const int row0 = blockIdx.x * 128;
  const int col0 = blockIdx.y * 256;
  gemm_core<1024, 1024, 16>(xb, wt, row0, col0, acc, lds);

  const int tid = threadIdx.x;
  const int l = tid & 63;
  const int wid = tid >> 6;
  const int wr = wid >> 2, wc = wid & 3;
  const int fr = l & 15, fq = l >> 4;
  const bool isQ = (col0 < 512);
  const bool isK = (!isQ) && (col0 < 1024);

  __syncthreads();  // all waves done with K-loop LDS

  // phase 1: acc -> LDS bf16 tile, pitch 264 ushorts
  constexpr int P = 264;
  #pragma unroll
  for (int m = 0; m < 4; ++m) {
    #pragma unroll
    for (int n = 0; n < 4; ++n) {
      const int c = wc * 64 + n * 16 + fr;
      #pragma unroll
      for (int j = 0; j < 4; ++j) {
        const int r = wr * 64 + m * 16 + fq * 4 + j;
        float v = acc[m][n][j];
        if (isQ || isK) v = elu1(v);
        lds[r * P + c] = f2bf(v);
      }
    }
  }
  __syncthreads();

  // phase 2: coalesced stores
  if (isQ) {
    const int r = tid >> 2;            // 0..127
    const int qd = (tid & 3) * 64;     // ushort offset in panel
    const ushort* src = &lds[r * P + qd];
    ushort* dst = &q[(size_t)(row0 + r) * 512 + col0 + qd];
    #pragma unroll
    for (int i = 0; i < 8; ++i)
      *(uint4*)(dst + i * 8) = *(const uint4*)(src + i * 8);
  } else {
    ushort* base = isK ? kT : vT;
    const int cl = wid * 32 + (l & 31);  // block-local feature col 0..255
    const int half = l >> 5;             // token half: rows 0-63 / 64-127
    const int d = col0 - (isK ? 512 : 1024) + cl;
    const int bh = (row0 >> 12) * 8 + (d >> 6);
    ushort* dstrow = base + ((size_t)bh * 64 + (d & 63)) * 4096 + (row0 & 4095) + half * 64;
    const ushort* srccol = &lds[(half * 64) * P + cl];
    #pragma unroll
    for (int rc = 0; rc < 8; ++rc) {
      ushort tmp[8];
      #pragma unroll
      for (int i = 0; i < 8; ++i) tmp[i] = srccol[(rc * 8 + i) * P];
      uint4 w;
      w.x = (unsigned)tmp[0] | ((unsigned)tmp[1] << 16);
      w.y = (unsigned)tmp[2] | ((unsigned)tmp[3] << 16);
      w.z = (unsigned)tmp[4] | ((unsigned)tmp[5] << 16);
      w.w = (unsigned)tmp[6] | ((unsigned)tmp[7] << 16);
      *(uint4*)(dstrow + rc * 8) = w;
    }
  }
}

// ---------- kernel 2: ctx partials via MFMA (R10 verbatim) ----------
__global__ __launch_bounds__(256) void ctx_mfma_kernel(const ushort* __restrict__ kT,
                                                       const ushort* __restrict__ vT,
                                                       float* __restrict__ part) {
  __shared__ ushort lds[16384];  // 32 KiB
  const int bh = blockIdx.x;
  const int sp = blockIdx.y;
  const int tid = threadIdx.x;
  const int l = tid & 63, wid = tid >> 6;
  const int fr = l & 15, fq = l >> 4;
  const int wr = wid >> 1, wc = wid & 1;

  const size_t base = (size_t)bh * 64 * 4096 + sp * 512;
  const int srow = tid >> 2;                     // 0..63
  const int lam = (tid & 3) ^ ((tid >> 3) & 3);  // logical 16B slot for phys (tid&3)
  const ushort* aG = kT + base + (size_t)srow * 4096 + lam * 8;
  const ushort* bG = vT + base + (size_t)srow * 4096 + lam * 8;

  auto stage = [&](int t) {
    ushort* d = lds + (t & 3) * 4096 + tid * 8;
    gload_lds16(aG + t * 32, d);
    gload_lds16(bG + t * 32, d + 2048);
  };

  const int sig = fq ^ ((fr >> 1) & 3);
  f32x4 acc[2][2] = {};

  auto compute = [&](int t) {
    const ushort* sb = lds + (t & 3) * 4096;
    bf16x8 av[2], bv[2];
    #pragma unroll
    for (int mm = 0; mm < 2; ++mm)
      av[mm] = *(const bf16x8*)&sb[(wr * 32 + mm * 16 + fr) * 32 + sig * 8];
    #pragma unroll
    for (int nn = 0; nn < 2; ++nn)
      bv[nn] = *(const bf16x8*)&sb[2048 + (wc * 32 + nn * 16 + fr) * 32 + sig * 8];
    #pragma unroll
    for (int mm = 0; mm < 2; ++mm)
      #pragma unroll
      for (int nn = 0; nn < 2; ++nn)
        acc[mm][nn] = __builtin_amdgcn_mfma_f32_16x16x32_bf16(av[mm], bv[nn], acc[mm][nn], 0, 0, 0);
  };

  constexpr int NT = 16;
  stage(0); stage(1); stage(2);
  for (int t = 0; t < NT; ++t) {
    if (t <= NT - 3) wait_vm<4>();
    else if (t == NT - 2) wait_vm<2>();
    else wait_vm<0>();
    hard_barrier();
    compute(t);
    hard_barrier();
    if (t + 3 < NT) stage(t + 3);
  }

  float* dst = part + ((size_t)sp * 32 + bh) * 4096;
  #pragma unroll
  for (int mm = 0; mm < 2; ++mm)
    #pragma unroll
    for (int nn = 0; nn < 2; ++nn)
      #pragma unroll
      for (int j = 0; j < 4; ++j)
        dst[(wr * 32 + mm * 16 + fq * 4 + j) * 64 + wc * 32 + nn * 16 + fr] = acc[mm][nn][j];
}

// ---------- kernel 3: W_eff^T (folds the 8-way split reduction) ----------
__global__ __launch_bounds__(256) void weff_kernel(const float* __restrict__ part,
                                                   const float* __restrict__ Wout,
                                                   ushort* __restrict__ weff) {
  const int bh = blockIdx.x;  // b*8+h
  const int h = bh & 7;
  const int m0 = blockIdx.y * 128;
  const int t = threadIdx.x;
  __shared__ float cs[64 * 64];
  __shared__ float ws[64][128];
  #pragma unroll
  for (int p = 0; p < 4; ++p) {
    const int idx = p * 1024 + t * 4;
    f32x4 s = {};
    #pragma unroll
    for (int sp = 0; sp < 8; ++sp)
      s += *(const f32x4*)&part[(size_t)sp * 131072 + (size_t)bh * 4096 + idx];
    *(f32x4*)&cs[idx] = s;
  }
  #pragma unroll
  for (int p = 0; p < 8; ++p) {
    const int e = (t >> 5) + p * 8;
    const int c = (t & 31) * 4;
    *(float4*)&ws[e][c] = *(const float4*)&Wout[(size_t)(h * 64 + e) * 1024 + m0 + c];
  }
  __syncthreads();
  const int m = t & 127;
  const int dh = (t >> 7) * 32;
  float acc[32] = {};
  for (int e = 0; e < 64; ++e) {
    const float w = ws[e][m];
    #pragma unroll
    for (int i = 0; i < 32; ++i)
      acc[i] += cs[(dh + i) * 64 + e] * w;
  }
  ushort* dst = weff + ((size_t)(bh >> 3) * 1024 + m0 + m) * 512 + h * 64 + dh;
  #pragma unroll
  for (int i = 0; i < 32; ++i) dst[i] = f2bf(acc[i]);
}

// ---------- kernel 4: out = q @ W_eff^T + b_out (fp32 out) ----------
__global__ __launch_bounds__(512, 2) void gemm_out_kernel(const ushort* __restrict__ q,
                                                          const ushort* __restrict__ weff,
                                                          const float* __restrict__ bout,
                                                          float* __restrict__ out) {
  __shared__ ushort lds[73728];  // 144 KiB
  f32x4 acc[4][4] = {};
  const int row0 = blockIdx.x * 128;
  const int col0 = blockIdx.y * 256;
  const int b = row0 >> 12;  // row0 / 4096
  gemm_core<512, 512, 8>(q, weff + (size_t)b * 1024 * 512, row0, col0, acc, lds);
  const int l = threadIdx.x & 63;
  const int wid = threadIdx.x >> 6;
  const int wr = wid >> 2, wc = wid & 3;
  const int fr = l & 15, fq = l >> 4;
  #pragma unroll
  for (int m = 0; m < 4; ++m) {
    #pragma unroll
    for (int n = 0; n < 4; ++n) {
      const int c = col0 + wc * 64 + n * 16 + fr;
      const float bb = bout[c];
      #pragma unroll
      for (int j = 0; j < 4; ++j) {
        const int r = row0 + wr * 64 + m * 16 + fq * 4 + j;
        out[(size_t)r * 1024 + c] = acc[m][n][j] + bb;
      }
    }
  }
}

extern "C" void kernel_launch(void* const* d_in, const int* in_sizes, int n_in,
                              void* d_out, int out_size, void* d_ws, size_t ws_size,
                              hipStream_t stream) {
  const float* x    = (const float*)d_in[0];
  const float* Wqkv = (const float*)d_in[1];
  const float* Wout = (const float*)d_in[2];
  const float* bout = (const float*)d_in[3];
  float* out = (float*)d_out;
  char* ws = (char*)d_ws;

  // workspace layout (bytes). part aliases xb (xb dead after gemm_qkv).
  ushort* xb   = (ushort*)(ws);              // 16384*1024*2  = 33554432
  float*  part = (float* )(ws);              // 8*32*4096*4   = 4194304 (alias)
  ushort* wt   = (ushort*)(ws + 33554432);   // 1536*1024*2   = 3145728
  ushort* q    = (ushort*)(ws + 36700160);   // 16384*512*2   = 16777216
  ushort* kT   = (ushort*)(ws + 53477376);   // 32*64*4096*2  = 16777216
  ushort* vT   = (ushort*)(ws + 70254592);   // 32*64*4096*2  = 16777216
  ushort* weff = (ushort*)(ws + 87556096);   // 4*1024*512*2  = 4194304

  prep_kernel<<<3584, 256, 0, stream>>>((const float4*)x, (ushort4*)xb, Wqkv, wt);
  gemm_qkv_kernel<<<dim3(128, 6), 512, 0, stream>>>(xb, wt, q, kT, vT);
  ctx_mfma_kernel<<<dim3(32, 8), 256, 0, stream>>>(kT, vT, part);
  weff_kernel<<<dim3(32, 8), 256, 0, stream>>>(part, Wout, weff);
  gemm_out_kernel<<<dim3(128, 4), 512, 0, stream>>>(q, weff, bout, out);
}

// Round 14
// 127.801 us; speedup vs baseline: 1.1632x; 1.1017x over previous
//
#include <hip/hip_runtime.h>
#include <hip/hip_bf16.h>
#include <cstdint>

typedef __attribute__((ext_vector_type(4))) float f32x4;
typedef __attribute__((ext_vector_type(8))) short bf16x8;

__device__ __forceinline__ ushort f2bf(float f) {
  unsigned u = __builtin_bit_cast(unsigned, f);
  u += 0x7fffu + ((u >> 16) & 1u);
  return (ushort)(u >> 16);
}

__device__ __forceinline__ void gload_lds16(const ushort* g, ushort* l) {
  __builtin_amdgcn_global_load_lds(
      (const __attribute__((address_space(1))) unsigned int*)g,
      (__attribute__((address_space(3))) unsigned int*)l, 16, 0, 0);
}

__device__ __forceinline__ void hard_barrier() {
  __builtin_amdgcn_sched_barrier(0);
  __builtin_amdgcn_s_barrier();
  __builtin_amdgcn_sched_barrier(0);
}

template <int N>
__device__ __forceinline__ void wait_vm() {
  if constexpr (N == 0) asm volatile("s_waitcnt vmcnt(0)" ::: "memory");
  else if constexpr (N == 2) asm volatile("s_waitcnt vmcnt(2)" ::: "memory");
  else if constexpr (N == 3) asm volatile("s_waitcnt vmcnt(3)" ::: "memory");
  else if constexpr (N == 4) asm volatile("s_waitcnt vmcnt(4)" ::: "memory");
  else static_assert(N < 0, "unsupported vmcnt");
}

__device__ __forceinline__ float elu1(float v) {
  return (v > 0.f) ? (v + 1.f) : __expf(v);
}

// ---------- kernel 0: fused prep (R10 verbatim) ----------
__global__ __launch_bounds__(256) void prep_kernel(const float4* __restrict__ x,
                                                   ushort4* __restrict__ xb,
                                                   const float* __restrict__ W,
                                                   ushort* __restrict__ Wt) {
  if (blockIdx.x < 2048) {
    const int n4 = 16384 * 1024 / 4;
    const int stride = 2048 * 256;
    for (int i = blockIdx.x * 256 + threadIdx.x; i < n4; i += stride) {
      float4 f = x[i];
      ushort4 o;
      o.x = f2bf(f.x); o.y = f2bf(f.y); o.z = f2bf(f.z); o.w = f2bf(f.w);
      xb[i] = o;
    }
  } else {
    __shared__ float tile[32][33];
    const int tb = blockIdx.x - 2048;     // 0..1535
    const int n0 = (tb % 48) * 32;
    const int k0 = (tb / 48) * 32;
    const int tx = threadIdx.x & 31;
    const int ty = threadIdx.x >> 5;      // 0..7
    #pragma unroll
    for (int p = 0; p < 4; ++p) {
      int k = k0 + ty + p * 8;
      tile[ty + p * 8][tx] = W[(size_t)k * 1536 + n0 + tx];
    }
    __syncthreads();
    #pragma unroll
    for (int p = 0; p < 4; ++p) {
      int n = n0 + ty + p * 8;
      Wt[(size_t)n * 1024 + k0 + tx] = f2bf(tile[tx][ty + p * 8]);
    }
  }
}

// ============================================================================
// BK=32 co-resident core: 128x256 tile, 512 threads = 8 waves (2M x 4N),
// wave tile 64x64. 3 LDS slots x 24KB (A 128x32 = 8KB | B 256x32 = 16KB)
// = 72 KiB -> TWO blocks resident per CU (16 waves): cross-block overlap
// hides vmcnt/barrier stalls (m114). Pipeline identical shape to the proven
// R1 core: stage(t+2); compute(t); counted vmcnt(3); one barrier per tile.
//   RAW: vmcnt(3) leaves only stage(t+2)'s 3 loads outstanding -> t+1 landed.
//   WAR: stage(t+2) writes slot (t-1)%3 whose reads finished before the
//        end-of-(t-1) barrier. Tails: vmcnt(0) at t=NT-2. Needs NT>=3.
// Swizzle (rule #21, linear gload_lds dest, pre-swizzled global source) for
// 64B rows (4 x 16B slots): phys slot = logical ^ (row&3).
//   Reads: row = {wr,wc}*64 + m*16 + fr -> row&3 = fr&3; sig = fq ^ (fr&3).
//   Bank check: group g = (fr&1)*4 + sig; all 8 groups hit exactly 8x -> free.
// ============================================================================
template <int LDA, int LDB, int NT>
__device__ __forceinline__ void gemm_core32(const ushort* __restrict__ A,
                                            const ushort* __restrict__ Bt,
                                            int row0, int col0, f32x4 acc[4][4],
                                            ushort* lds) {
  const int tid = threadIdx.x;
  const int l = tid & 63;
  const int wid = tid >> 6;
  const int fr = l & 15;
  const int fq = l >> 4;
  const int wr = wid >> 2;
  const int wc = wid & 3;

  const int sc = ((tid & 3) ^ ((tid >> 2) & 3)) * 8;  // pre-swizzled source col
  const ushort* aS = A + (size_t)(row0 + (tid >> 2)) * LDA + sc;
  const ushort* bS = Bt + (size_t)(col0 + (tid >> 2)) * LDB + sc;

  auto stage = [&](int t) {
    ushort* base = lds + (t % 3) * 12288 + tid * 8;
    gload_lds16(aS + t * 32, base);
    gload_lds16(bS + t * 32, base + 4096);
    gload_lds16(bS + (size_t)128 * LDB + t * 32, base + 8192);
  };

  const int sig = fq ^ (fr & 3);
  const int aOff = wr * 2048 + fr * 32 + sig * 8;
  const int bOff = 4096 + wc * 2048 + fr * 32 + sig * 8;

  auto compute = [&](int t) {
    const ushort* sb = lds + (t % 3) * 12288;
    bf16x8 av[4], bv[4];
    #pragma unroll
    for (int m = 0; m < 4; ++m) av[m] = *(const bf16x8*)(sb + aOff + m * 512);
    #pragma unroll
    for (int n = 0; n < 4; ++n) bv[n] = *(const bf16x8*)(sb + bOff + n * 512);
    __builtin_amdgcn_s_setprio(1);
    #pragma unroll
    for (int m = 0; m < 4; ++m)
      #pragma unroll
      for (int n = 0; n < 4; ++n)
        acc[m][n] = __builtin_amdgcn_mfma_f32_16x16x32_bf16(av[m], bv[n], acc[m][n], 0, 0, 0);
    __builtin_amdgcn_s_setprio(0);
  };

  stage(0);
  stage(1);
  wait_vm<3>();
  hard_barrier();

  #pragma unroll 3
  for (int t = 0; t < NT; ++t) {
    if (t + 2 < NT) stage(t + 2);
    compute(t);
    if (t + 2 < NT) {
      wait_vm<3>();
      hard_barrier();
    } else if (t + 1 < NT) {
      wait_vm<0>();
      hard_barrier();
    }
  }
}

// ---------- kernel 1: qkv GEMM; epilogue emits q (elu+1), kT (elu+1), vT ----
__global__ __launch_bounds__(512, 4) void gemm_qkv_kernel(const ushort* __restrict__ xb,
                                                          const ushort* __restrict__ wt,
                                                          ushort* __restrict__ q,
                                                          ushort* __restrict__ kT,
                                                          ushort* __restrict__ vT) {
  __shared__ ushort lds[36864];  // 72 KiB -> 2 blocks/CU
  f32x4 acc[4][4] = {};
  const int row0 = blockIdx.x * 128;
  const int col0 = blockIdx.y * 256;
  gemm_core32<1024, 1024, 32>(xb, wt, row0, col0, acc, lds);
  const int l = threadIdx.x & 63;
  const int wid = threadIdx.x >> 6;
  const int wr = wid >> 2, wc = wid & 3;
  const int fr = l & 15, fq = l >> 4;
  #pragma unroll
  for (int m = 0; m < 4; ++m) {
    #pragma unroll
    for (int n = 0; n < 4; ++n) {
      const int c = col0 + wc * 64 + n * 16 + fr;
      const int r0 = row0 + wr * 64 + m * 16 + fq * 4;  // j=0..3 consecutive rows
      if (c < 512) {
        #pragma unroll
        for (int j = 0; j < 4; ++j)
          q[(size_t)(r0 + j) * 512 + c] = f2bf(elu1(acc[m][n][j]));
      } else if (c < 1024) {
        const int d = c - 512;
        const int bh = (r0 >> 12) * 8 + (d >> 6);
        const int nn = r0 & 4095;
        ushort4 o;
        o.x = f2bf(elu1(acc[m][n][0]));
        o.y = f2bf(elu1(acc[m][n][1]));
        o.z = f2bf(elu1(acc[m][n][2]));
        o.w = f2bf(elu1(acc[m][n][3]));
        *(ushort4*)&kT[((size_t)bh * 64 + (d & 63)) * 4096 + nn] = o;
      } else {
        const int d = c - 1024;
        const int bh = (r0 >> 12) * 8 + (d >> 6);
        const int nn = r0 & 4095;
        ushort4 o;
        o.x = f2bf(acc[m][n][0]);
        o.y = f2bf(acc[m][n][1]);
        o.z = f2bf(acc[m][n][2]);
        o.w = f2bf(acc[m][n][3]);
        *(ushort4*)&vT[((size_t)bh * 64 + (d & 63)) * 4096 + nn] = o;
      }
    }
  }
}

// ---------- kernel 2: ctx partials via MFMA (R10 verbatim) ----------
__global__ __launch_bounds__(256) void ctx_mfma_kernel(const ushort* __restrict__ kT,
                                                       const ushort* __restrict__ vT,
                                                       float* __restrict__ part) {
  __shared__ ushort lds[16384];  // 32 KiB
  const int bh = blockIdx.x;
  const int sp = blockIdx.y;
  const int tid = threadIdx.x;
  const int l = tid & 63, wid = tid >> 6;
  const int fr = l & 15, fq = l >> 4;
  const int wr = wid >> 1, wc = wid & 1;

  const size_t base = (size_t)bh * 64 * 4096 + sp * 512;
  const int srow = tid >> 2;                     // 0..63
  const int lam = (tid & 3) ^ ((tid >> 3) & 3);  // logical 16B slot for phys (tid&3)
  const ushort* aG = kT + base + (size_t)srow * 4096 + lam * 8;
  const ushort* bG = vT + base + (size_t)srow * 4096 + lam * 8;

  auto stage = [&](int t) {
    ushort* d = lds + (t & 3) * 4096 + tid * 8;
    gload_lds16(aG + t * 32, d);
    gload_lds16(bG + t * 32, d + 2048);
  };

  const int sig = fq ^ ((fr >> 1) & 3);
  f32x4 acc[2][2] = {};

  auto compute = [&](int t) {
    const ushort* sb = lds + (t & 3) * 4096;
    bf16x8 av[2], bv[2];
    #pragma unroll
    for (int mm = 0; mm < 2; ++mm)
      av[mm] = *(const bf16x8*)&sb[(wr * 32 + mm * 16 + fr) * 32 + sig * 8];
    #pragma unroll
    for (int nn = 0; nn < 2; ++nn)
      bv[nn] = *(const bf16x8*)&sb[2048 + (wc * 32 + nn * 16 + fr) * 32 + sig * 8];
    #pragma unroll
    for (int mm = 0; mm < 2; ++mm)
      #pragma unroll
      for (int nn = 0; nn < 2; ++nn)
        acc[mm][nn] = __builtin_amdgcn_mfma_f32_16x16x32_bf16(av[mm], bv[nn], acc[mm][nn], 0, 0, 0);
  };

  constexpr int NT = 16;
  stage(0); stage(1); stage(2);
  for (int t = 0; t < NT; ++t) {
    if (t <= NT - 3) wait_vm<4>();
    else if (t == NT - 2) wait_vm<2>();
    else wait_vm<0>();
    hard_barrier();
    compute(t);
    hard_barrier();
    if (t + 3 < NT) stage(t + 3);
  }

  float* dst = part + ((size_t)sp * 32 + bh) * 4096;
  #pragma unroll
  for (int mm = 0; mm < 2; ++mm)
    #pragma unroll
    for (int nn = 0; nn < 2; ++nn)
      #pragma unroll
      for (int j = 0; j < 4; ++j)
        dst[(wr * 32 + mm * 16 + fq * 4 + j) * 64 + wc * 32 + nn * 16 + fr] = acc[mm][nn][j];
}

// ---------- kernel 3: W_eff^T (folds the 8-way split reduction) ----------
__global__ __launch_bounds__(256) void weff_kernel(const float* __restrict__ part,
                                                   const float* __restrict__ Wout,
                                                   ushort* __restrict__ weff) {
  const int bh = blockIdx.x;  // b*8+h
  const int h = bh & 7;
  const int m0 = blockIdx.y * 128;
  const int t = threadIdx.x;
  __shared__ float cs[64 * 64];
  __shared__ float ws[64][128];
  #pragma unroll
  for (int p = 0; p < 4; ++p) {
    const int idx = p * 1024 + t * 4;
    f32x4 s = {};
    #pragma unroll
    for (int sp = 0; sp < 8; ++sp)
      s += *(const f32x4*)&part[(size_t)sp * 131072 + (size_t)bh * 4096 + idx];
    *(f32x4*)&cs[idx] = s;
  }
  #pragma unroll
  for (int p = 0; p < 8; ++p) {
    const int e = (t >> 5) + p * 8;
    const int c = (t & 31) * 4;
    *(float4*)&ws[e][c] = *(const float4*)&Wout[(size_t)(h * 64 + e) * 1024 + m0 + c];
  }
  __syncthreads();
  const int m = t & 127;
  const int dh = (t >> 7) * 32;
  float acc[32] = {};
  for (int e = 0; e < 64; ++e) {
    const float w = ws[e][m];
    #pragma unroll
    for (int i = 0; i < 32; ++i)
      acc[i] += cs[(dh + i) * 64 + e] * w;
  }
  ushort* dst = weff + ((size_t)(bh >> 3) * 1024 + m0 + m) * 512 + h * 64 + dh;
  #pragma unroll
  for (int i = 0; i < 32; ++i) dst[i] = f2bf(acc[i]);
}

// ---------- kernel 4: out = q @ W_eff^T + b_out (fp32 out) ----------
__global__ __launch_bounds__(512, 4) void gemm_out_kernel(const ushort* __restrict__ q,
                                                          const ushort* __restrict__ weff,
                                                          const float* __restrict__ bout,
                                                          float* __restrict__ out) {
  __shared__ ushort lds[36864];  // 72 KiB -> 2 blocks/CU, grid 512 = 1 round
  f32x4 acc[4][4] = {};
  const int row0 = blockIdx.x * 128;
  const int col0 = blockIdx.y * 256;
  const int b = row0 >> 12;  // row0 / 4096
  gemm_core32<512, 512, 16>(q, weff + (size_t)b * 1024 * 512, row0, col0, acc, lds);
  const int l = threadIdx.x & 63;
  const int wid = threadIdx.x >> 6;
  const int wr = wid >> 2, wc = wid & 3;
  const int fr = l & 15, fq = l >> 4;
  #pragma unroll
  for (int m = 0; m < 4; ++m) {
    #pragma unroll
    for (int n = 0; n < 4; ++n) {
      const int c = col0 + wc * 64 + n * 16 + fr;
      const float bb = bout[c];
      #pragma unroll
      for (int j = 0; j < 4; ++j) {
        const int r = row0 + wr * 64 + m * 16 + fq * 4 + j;
        out[(size_t)r * 1024 + c] = acc[m][n][j] + bb;
      }
    }
  }
}

extern "C" void kernel_launch(void* const* d_in, const int* in_sizes, int n_in,
                              void* d_out, int out_size, void* d_ws, size_t ws_size,
                              hipStream_t stream) {
  const float* x    = (const float*)d_in[0];
  const float* Wqkv = (const float*)d_in[1];
  const float* Wout = (const float*)d_in[2];
  const float* bout = (const float*)d_in[3];
  float* out = (float*)d_out;
  char* ws = (char*)d_ws;

  // workspace layout (bytes). part aliases xb (xb dead after gemm_qkv).
  ushort* xb   = (ushort*)(ws);              // 16384*1024*2  = 33554432
  float*  part = (float* )(ws);              // 8*32*4096*4   = 4194304 (alias)
  ushort* wt   = (ushort*)(ws + 33554432);   // 1536*1024*2   = 3145728
  ushort* q    = (ushort*)(ws + 36700160);   // 16384*512*2   = 16777216
  ushort* kT   = (ushort*)(ws + 53477376);   // 32*64*4096*2  = 16777216
  ushort* vT   = (ushort*)(ws + 70254592);   // 32*64*4096*2  = 16777216
  ushort* weff = (ushort*)(ws + 87556096);   // 4*1024*512*2  = 4194304

  prep_kernel<<<3584, 256, 0, stream>>>((const float4*)x, (ushort4*)xb, Wqkv, wt);
  gemm_qkv_kernel<<<dim3(128, 6), 512, 0, stream>>>(xb, wt, q, kT, vT);
  ctx_mfma_kernel<<<dim3(32, 8), 256, 0, stream>>>(kT, vT, part);
  weff_kernel<<<dim3(32, 8), 256, 0, stream>>>(part, Wout, weff);
  gemm_out_kernel<<<dim3(128, 4), 512, 0, stream>>>(q, weff, bout, out);
}